// Round 4
// baseline (120.175 us; speedup 1.0000x reference)
//
#include <hip/hip_runtime.h>
#include <hip/hip_bf16.h>

#define N 4096
#define D 512
#define MARGIN 0.5f
#define BETA 10.0f

typedef __attribute__((ext_vector_type(8))) short short8;
typedef __attribute__((ext_vector_type(4))) float floatx4;

__device__ inline unsigned short f2bf(float f) {
    unsigned u = __float_as_uint(f);
    u += 0x7fffu + ((u >> 16) & 1u);   // round-to-nearest-even
    return (unsigned short)(u >> 16);
}

// ---- Kernel 1: f32 -> bf16 convert + zero the accumulator buffers ----
__global__ __launch_bounds__(256) void convert_bf16_kernel(
        const float4* __restrict__ in, ushort4* __restrict__ out,
        float* __restrict__ sums /* 2*N floats to zero */) {
    int idx = blockIdx.x * 256 + threadIdx.x;
    if (idx < 2 * N) sums[idx] = 0.f;
    float4 v = in[idx];
    ushort4 o;
    o.x = f2bf(v.x); o.y = f2bf(v.y); o.z = f2bf(v.z); o.w = f2bf(v.w);
    out[idx] = o;
}

// ---- Kernel 2: fused sim-GEMM + masked exp sums, upper triangle ----
// NO LDS staging, NO barriers in the K-loop: MFMA fragments are loaded
// directly from global (4 MB input is L2-resident; intra-block reuse hits
// L1). Register double-buffer prefetches kt+1 during kt's MFMAs, letting
// the compiler emit MFMA<->load interleave with partial vmcnt waits —
// the structure the 2-barrier LDS K-loop cannot express (R2 was
// barrier-drain-bound at ~40us for 8.9 GFLOP).
__global__ __launch_bounds__(256, 3) void ms_loss_gemm(
        const unsigned short* __restrict__ Ebf,
        const int* __restrict__ labels,
        float* __restrict__ pos_sum,
        float* __restrict__ neg_sum) {
    __shared__ int rlab[128];
    __shared__ int clab[128];

    // decode linear block id -> upper-triangle tile (bi, bj), bi <= bj
    int t = blockIdx.x;
    int bi = 0;
    while (t >= (32 - bi)) { t -= (32 - bi); ++bi; }
    const int bj = bi + t;
    const bool diag = (bi == bj);

    const int tid  = threadIdx.x;
    const int wave = tid >> 6;
    const int lane = tid & 63;
    const int quad = lane >> 4;      // 0..3
    const int lcol = lane & 15;      // 0..15
    const int wrow = wave >> 1;      // 0..1
    const int wcol = wave & 1;       // 0..1
    const int ibase = bi * 128;
    const int jbase = bj * 128;

    if (tid < 128)       rlab[tid]       = labels[ibase + tid];
    else                 clab[tid - 128] = labels[jbase + tid - 128];
    __syncthreads();     // the only barrier: labels visible for epilogue

    // Per-lane fragment base addresses (A-frag layout for 16x16x32 bf16:
    // lane holds E[row = base + lcol][k = quad*8 .. +8] -> 16 B at
    // row*1024 + quad*16; advance 64 B per kt).
    const char* Eb = (const char*)Ebf;
    const char* aBase[4];
    const char* bBase[4];
#pragma unroll
    for (int x = 0; x < 4; ++x) {
        int r = ibase + wrow * 64 + x * 16 + lcol;
        int c = jbase + wcol * 64 + x * 16 + lcol;
        aBase[x] = Eb + (size_t)r * (D * 2) + quad * 16;
        bBase[x] = Eb + (size_t)c * (D * 2) + quad * 16;
    }

    floatx4 acc[4][4];
#pragma unroll
    for (int mt = 0; mt < 4; ++mt)
#pragma unroll
        for (int nt = 0; nt < 4; ++nt)
            acc[mt][nt] = (floatx4){0.f, 0.f, 0.f, 0.f};

    short8 abuf[2][4], bbuf[2][4];
#pragma unroll
    for (int x = 0; x < 4; ++x) {
        abuf[0][x] = *(const short8*)(aBase[x]);
        bbuf[0][x] = *(const short8*)(bBase[x]);
    }

#pragma unroll
    for (int kt = 0; kt < D / 32; ++kt) {
        const int cur = kt & 1, nxt = cur ^ 1;
        if (kt < D / 32 - 1) {
            const int off = (kt + 1) * 64;
#pragma unroll
            for (int x = 0; x < 4; ++x) {
                abuf[nxt][x] = *(const short8*)(aBase[x] + off);
                bbuf[nxt][x] = *(const short8*)(bBase[x] + off);
            }
        }
#pragma unroll
        for (int mt = 0; mt < 4; ++mt)
#pragma unroll
            for (int nt = 0; nt < 4; ++nt)
                acc[mt][nt] = __builtin_amdgcn_mfma_f32_16x16x32_bf16(
                    abuf[cur][mt], bbuf[cur][nt], acc[mt][nt], 0, 0, 0);
    }

    // ---- epilogue ----
    // C layout (m89-verified): col = lane&15, row = quad*4 + reg
    int ljv[4], gjv[4];
#pragma unroll
    for (int nt = 0; nt < 4; ++nt) {
        int cl = wcol * 64 + nt * 16 + lcol;
        ljv[nt] = clab[cl];
        gjv[nt] = jbase + cl;
    }

    float colp[4] = {0.f, 0.f, 0.f, 0.f};
    float coln[4] = {0.f, 0.f, 0.f, 0.f};

#pragma unroll
    for (int mt = 0; mt < 4; ++mt) {
#pragma unroll
        for (int reg = 0; reg < 4; ++reg) {
            int rl = wrow * 64 + mt * 16 + quad * 4 + reg;
            int gi = ibase + rl;
            int li = rlab[rl];
            float p = 0.f, ng = 0.f;
#pragma unroll
            for (int nt = 0; nt < 4; ++nt) {
                float s = acc[mt][nt][reg];
                if (gi != gjv[nt]) {
                    if (li == ljv[nt]) {
                        float e = __expf(MARGIN - s);          // alpha = 1
                        p += e;  colp[nt] += e;
                    } else {
                        float e = __expf(BETA * (s - MARGIN));
                        ng += e; coln[nt] += e;
                    }
                }
            }
            // row-sum: reduce across the 16 lcol lanes (distinct cols)
            p  += __shfl_xor(p, 1);   ng += __shfl_xor(ng, 1);
            p  += __shfl_xor(p, 2);   ng += __shfl_xor(ng, 2);
            p  += __shfl_xor(p, 4);   ng += __shfl_xor(ng, 4);
            p  += __shfl_xor(p, 8);   ng += __shfl_xor(ng, 8);
            if (lcol == 0) {
                atomicAdd(&pos_sum[gi], p);
                atomicAdd(&neg_sum[gi], ng);
            }
        }
    }

    // col-sum (mirror credit), off-diagonal blocks only
    if (!diag) {
#pragma unroll
        for (int nt = 0; nt < 4; ++nt) {
            float cp = colp[nt], cn = coln[nt];
            cp += __shfl_xor(cp, 16);  cn += __shfl_xor(cn, 16);
            cp += __shfl_xor(cp, 32);  cn += __shfl_xor(cn, 32);
            if (quad == 0) {
                int gj = gjv[nt];
                atomicAdd(&pos_sum[gj], cp);
                atomicAdd(&neg_sum[gj], cn);
            }
        }
    }
}

// ---- Kernel 3: finalize ----
__global__ __launch_bounds__(256) void finalize_kernel(
        const float4* __restrict__ pos4, const float4* __restrict__ neg4,
        float* __restrict__ out) {
    __shared__ float sb[256];
    __shared__ int   sc[256];
    const int tid = threadIdx.x;
    float tot = 0.f;
    int cnt = 0;
#pragma unroll
    for (int it = 0; it < N / 4 / 256; ++it) {
        int i = it * 256 + tid;
        float4 p = pos4[i];
        float4 ng = neg4[i];
        const float* pp = (const float*)&p;
        const float* nn = (const float*)&ng;
#pragma unroll
        for (int j = 0; j < 4; ++j) {
            if (pp[j] > 0.f && nn[j] > 0.f) {
                tot += log1pf(pp[j]) + (1.0f / BETA) * log1pf(nn[j]);
                cnt += 1;
            }
        }
    }
    sb[tid] = tot; sc[tid] = cnt;
    __syncthreads();
    for (int s = 128; s > 0; s >>= 1) {
        if (tid < s) { sb[tid] += sb[tid + s]; sc[tid] += sc[tid + s]; }
        __syncthreads();
    }
    if (tid == 0) out[0] = (sc[0] > 0) ? sb[0] / (float)sc[0] : 0.f;
}

extern "C" void kernel_launch(void* const* d_in, const int* in_sizes, int n_in,
                              void* d_out, int out_size, void* d_ws, size_t ws_size,
                              hipStream_t stream) {
    const float* emb   = (const float*)d_in[0];
    const int* labels  = (const int*)d_in[1];
    float* out         = (float*)d_out;

    char* ws = (char*)d_ws;
    unsigned short* Ebf = (unsigned short*)ws;                 // 4 MB
    float* pos_sum = (float*)(ws + (size_t)N * D * 2);         // 16 KB
    float* neg_sum = pos_sum + N;                              // 16 KB

    convert_bf16_kernel<<<(N * D / 4) / 256, 256, 0, stream>>>(
        (const float4*)emb, (ushort4*)Ebf, pos_sum);

    ms_loss_gemm<<<(32 * 33) / 2, 256, 0, stream>>>(Ebf, labels, pos_sum, neg_sum);

    finalize_kernel<<<1, 256, 0, stream>>>(
        (const float4*)pos_sum, (const float4*)neg_sum, out);
}

// Round 5
// 99.368 us; speedup vs baseline: 1.2094x; 1.2094x over previous
//
#include <hip/hip_runtime.h>
#include <hip/hip_bf16.h>

#define N 4096
#define D 512
#define MARGIN 0.5f
#define BETA 10.0f

typedef __attribute__((ext_vector_type(8))) short short8;
typedef __attribute__((ext_vector_type(4))) float floatx4;

__device__ inline unsigned short f2bf(float f) {
    unsigned u = __float_as_uint(f);
    u += 0x7fffu + ((u >> 16) & 1u);   // round-to-nearest-even
    return (unsigned short)(u >> 16);
}

#define GLOAD_LDS16(gp, lp)                                             \
    __builtin_amdgcn_global_load_lds(                                   \
        (const __attribute__((address_space(1))) void*)(gp),            \
        (__attribute__((address_space(3))) void*)(lp), 16, 0, 0)

// ---- Kernel 1: f32 -> bf16 convert + zero the accumulator buffers ----
__global__ __launch_bounds__(256) void convert_bf16_kernel(
        const float4* __restrict__ in, ushort4* __restrict__ out,
        float* __restrict__ sums /* 2*N floats to zero */) {
    int idx = blockIdx.x * 256 + threadIdx.x;
    if (idx < 2 * N) sums[idx] = 0.f;
    float4 v = in[idx];
    ushort4 o;
    o.x = f2bf(v.x); o.y = f2bf(v.y); o.z = f2bf(v.z); o.w = f2bf(v.w);
    out[idx] = o;
}

// ---- Kernel 2: fused sim-GEMM + masked exp sums, upper triangle ----
// BK=64, double-buffered LDS, ONE barrier per K-iter: stage kt+1 into
// buf[nxt] immediately after the barrier, compute kt from buf[cur]. The
// vmcnt(0) drain before each barrier then waits on loads that already had
// a full 32-MFMA phase to complete (R3 was serial stage->drain->compute,
// 2 barriers x 16 iters => ~27us; R4 direct-global was latency-bound 54us).
// LDS chunk-XOR swizzle (chunk ^ (row&7), applied on the GLOBAL source
// address since global_load_lds dest must be lane-contiguous) makes the
// 128B-stride ds_read_b128 the minimal 8-phase conflict-free pattern.
__global__ __launch_bounds__(256, 2) void ms_loss_gemm(
        const unsigned short* __restrict__ Ebf,
        const int* __restrict__ labels,
        float* __restrict__ pos_sum,
        float* __restrict__ neg_sum) {
    __shared__ char Als[2][128 * 128];   // 2 x 16 KB, [row][128B of k]
    __shared__ char Bls[2][128 * 128];   // 2 x 16 KB
    __shared__ int rlab[128];
    __shared__ int clab[128];

    // decode linear block id -> upper-triangle tile (bi, bj), bi <= bj
    int t = blockIdx.x;
    int bi = 0;
    while (t >= (32 - bi)) { t -= (32 - bi); ++bi; }
    const int bj = bi + t;
    const bool diag = (bi == bj);

    const int tid  = threadIdx.x;
    const int wave = tid >> 6;
    const int lane = tid & 63;
    const int quad = lane >> 4;      // 0..3
    const int lcol = lane & 15;      // 0..15
    const int wrow = wave >> 1;      // 0..1
    const int wcol = wave & 1;       // 0..1
    const int ibase = bi * 128;
    const int jbase = bj * 128;

    if (tid < 128)       rlab[tid]       = labels[ibase + tid];
    else                 clab[tid - 128] = labels[jbase + tid - 128];

    floatx4 acc[4][4];
#pragma unroll
    for (int mt = 0; mt < 4; ++mt)
#pragma unroll
        for (int nt = 0; nt < 4; ++nt)
            acc[mt][nt] = (floatx4){0.f, 0.f, 0.f, 0.f};

    const char* Eb = (const char*)Ebf;                 // row stride 1024 B
    // staging: each DMA instr = 8 rows x 128 B; 4 instrs/thread per tile.
    const int srow = lane >> 3;                        // 0..7 (row within group)
    const int sck  = ((lane & 7) ^ (lane >> 3)) * 16;  // swizzled global chunk
    const size_t arow0 = (size_t)(ibase + wave * 8 + srow) * 1024 + sck;
    const size_t brow0 = (size_t)(jbase + wave * 8 + srow) * 1024 + sck;
    const int ldso0 = wave * 1024 + lane * 16;

    // frag-read swizzle term: row&7 == lcol&7 for all frag rows
    const int rsw = (lcol & 7);

#define STAGE(sel, kt_)                                                    \
    {                                                                      \
        const int kb_ = (kt_) * 128;                                       \
        _Pragma("unroll")                                                  \
        for (int it = 0; it < 4; ++it) {                                   \
            GLOAD_LDS16(Eb + arow0 + (size_t)it * 32 * 1024 + kb_,         \
                        Als[sel] + ldso0 + it * 4096);                     \
            if (!diag)                                                     \
                GLOAD_LDS16(Eb + brow0 + (size_t)it * 32 * 1024 + kb_,     \
                            Bls[sel] + ldso0 + it * 4096);                 \
        }                                                                  \
    }

    STAGE(0, 0);

#pragma unroll
    for (int kt = 0; kt < D / 64; ++kt) {
        const int cur = kt & 1;
        __syncthreads();   // drains cur's staging; syncs prev reads + labels
        if (kt < D / 64 - 1) STAGE(cur ^ 1, kt + 1);

        const char* Ac = Als[cur];
        const char* Bc = diag ? Als[cur] : Bls[cur];
#pragma unroll
        for (int s = 0; s < 2; ++s) {
            short8 a[4], b[4];
            const int rchunk = ((s * 4 + quad) ^ rsw) * 16;
#pragma unroll
            for (int mt = 0; mt < 4; ++mt) {
                int r = wrow * 64 + mt * 16 + lcol;
                a[mt] = *(const short8*)(Ac + r * 128 + rchunk);
            }
#pragma unroll
            for (int nt = 0; nt < 4; ++nt) {
                int c = wcol * 64 + nt * 16 + lcol;
                b[nt] = *(const short8*)(Bc + c * 128 + rchunk);
            }
#pragma unroll
            for (int mt = 0; mt < 4; ++mt)
#pragma unroll
                for (int nt = 0; nt < 4; ++nt)
                    acc[mt][nt] = __builtin_amdgcn_mfma_f32_16x16x32_bf16(
                        a[mt], b[nt], acc[mt][nt], 0, 0, 0);
        }
    }

    // ---- epilogue ----
    // C layout (m89-verified): col = lane&15, row = quad*4 + reg
    int ljv[4], gjv[4];
#pragma unroll
    for (int nt = 0; nt < 4; ++nt) {
        int cl = wcol * 64 + nt * 16 + lcol;
        ljv[nt] = clab[cl];
        gjv[nt] = jbase + cl;
    }

    float colp[4] = {0.f, 0.f, 0.f, 0.f};
    float coln[4] = {0.f, 0.f, 0.f, 0.f};

#pragma unroll
    for (int mt = 0; mt < 4; ++mt) {
#pragma unroll
        for (int reg = 0; reg < 4; ++reg) {
            int rl = wrow * 64 + mt * 16 + quad * 4 + reg;
            int gi = ibase + rl;
            int li = rlab[rl];
            float p = 0.f, ng = 0.f;
#pragma unroll
            for (int nt = 0; nt < 4; ++nt) {
                float s = acc[mt][nt][reg];
                if (gi != gjv[nt]) {
                    if (li == ljv[nt]) {
                        float e = __expf(MARGIN - s);          // alpha = 1
                        p += e;  colp[nt] += e;
                    } else {
                        float e = __expf(BETA * (s - MARGIN));
                        ng += e; coln[nt] += e;
                    }
                }
            }
            // row-sum: reduce across the 16 lcol lanes (distinct cols)
            p  += __shfl_xor(p, 1);   ng += __shfl_xor(ng, 1);
            p  += __shfl_xor(p, 2);   ng += __shfl_xor(ng, 2);
            p  += __shfl_xor(p, 4);   ng += __shfl_xor(ng, 4);
            p  += __shfl_xor(p, 8);   ng += __shfl_xor(ng, 8);
            if (lcol == 0) {
                atomicAdd(&pos_sum[gi], p);
                atomicAdd(&neg_sum[gi], ng);
            }
        }
    }

    // col-sum (mirror credit), off-diagonal blocks only
    if (!diag) {
#pragma unroll
        for (int nt = 0; nt < 4; ++nt) {
            float cp = colp[nt], cn = coln[nt];
            cp += __shfl_xor(cp, 16);  cn += __shfl_xor(cn, 16);
            cp += __shfl_xor(cp, 32);  cn += __shfl_xor(cn, 32);
            if (quad == 0) {
                int gj = gjv[nt];
                atomicAdd(&pos_sum[gj], cp);
                atomicAdd(&neg_sum[gj], cn);
            }
        }
    }
}

// ---- Kernel 3: finalize ----
__global__ __launch_bounds__(256) void finalize_kernel(
        const float4* __restrict__ pos4, const float4* __restrict__ neg4,
        float* __restrict__ out) {
    __shared__ float sb[256];
    __shared__ int   sc[256];
    const int tid = threadIdx.x;
    float tot = 0.f;
    int cnt = 0;
#pragma unroll
    for (int it = 0; it < N / 4 / 256; ++it) {
        int i = it * 256 + tid;
        float4 p = pos4[i];
        float4 ng = neg4[i];
        const float* pp = (const float*)&p;
        const float* nn = (const float*)&ng;
#pragma unroll
        for (int j = 0; j < 4; ++j) {
            if (pp[j] > 0.f && nn[j] > 0.f) {
                tot += log1pf(pp[j]) + (1.0f / BETA) * log1pf(nn[j]);
                cnt += 1;
            }
        }
    }
    sb[tid] = tot; sc[tid] = cnt;
    __syncthreads();
    for (int s = 128; s > 0; s >>= 1) {
        if (tid < s) { sb[tid] += sb[tid + s]; sc[tid] += sc[tid + s]; }
        __syncthreads();
    }
    if (tid == 0) out[0] = (sc[0] > 0) ? sb[0] / (float)sc[0] : 0.f;
}

extern "C" void kernel_launch(void* const* d_in, const int* in_sizes, int n_in,
                              void* d_out, int out_size, void* d_ws, size_t ws_size,
                              hipStream_t stream) {
    const float* emb   = (const float*)d_in[0];
    const int* labels  = (const int*)d_in[1];
    float* out         = (float*)d_out;

    char* ws = (char*)d_ws;
    unsigned short* Ebf = (unsigned short*)ws;                 // 4 MB
    float* pos_sum = (float*)(ws + (size_t)N * D * 2);         // 16 KB
    float* neg_sum = pos_sum + N;                              // 16 KB

    convert_bf16_kernel<<<(N * D / 4) / 256, 256, 0, stream>>>(
        (const float4*)emb, (ushort4*)Ebf, pos_sum);

    ms_loss_gemm<<<(32 * 33) / 2, 256, 0, stream>>>(Ebf, labels, pos_sum, neg_sum);

    finalize_kernel<<<1, 256, 0, stream>>>(
        (const float4*)pos_sum, (const float4*)neg_sum, out);
}